// Round 6
// baseline (3845.762 us; speedup 1.0000x reference)
//
#include <hip/hip_runtime.h>
#include <math.h>

#define N_UE 16384
#define N_AP 128
#define NE   2097152
#define NSB  256               // sort blocks
#define EPSB (NE / NSB)        // 8192 edges per sort block
#define EB   1024              // fused edge blocks
#define NPART EB
#define CHUNK (NE / EB)        // 2048 edges per block
#define SSZ  256               // edges per stage
#define NSTG (CHUNK / SSZ)     // 8 stages
#define NROWS 48               // LDS agg_ue rows per block (span ~27 expected)

// ---------------------------------------------------------------------------
// init: Qua1[u][d] = x_ue[u]*Wm1_ua[0][d] + bm1_ua[d];  Pau1[a][d] = bm1_au[d]
// ---------------------------------------------------------------------------
__global__ __launch_bounds__(256) void init_kernel(
    const float* __restrict__ x_ue, const float* __restrict__ Wm1_ua,
    const float* __restrict__ bm1_ua, const float* __restrict__ bm1_au,
    float* __restrict__ Qua, float* __restrict__ Pau)
{
    int i = blockIdx.x * 256 + threadIdx.x;
    int d = i & 31;
    Qua[i] = fmaf(x_ue[i >> 5], Wm1_ua[d], bm1_ua[d]);
    if (i < N_AP * 32) Pau[i] = bm1_au[d];
}

// ---------------------------------------------------------------------------
// src-sort: histogram -> column scan -> prefix scan -> scatter
// ---------------------------------------------------------------------------
__global__ __launch_bounds__(256) void hist_src(
    const int* __restrict__ src, int* __restrict__ histS)
{
    __shared__ int h[N_UE];
    for (int i = threadIdx.x; i < N_UE; i += 256) h[i] = 0;
    __syncthreads();
    const int beg = blockIdx.x * EPSB;
    for (int e = beg + threadIdx.x; e < beg + EPSB; e += 256)
        atomicAdd(&h[src[e]], 1);
    __syncthreads();
    for (int i = threadIdx.x; i < N_UE; i += 256) histS[blockIdx.x * N_UE + i] = h[i];
}

__global__ __launch_bounds__(256) void colscan_kernel(
    const int* __restrict__ histS, int* __restrict__ baseS, int* __restrict__ cnt)
{
    const int u = blockIdx.x * 256 + threadIdx.x;
    int run = 0;
    for (int b = 0; b < NSB; ++b) {
        int t = histS[b * N_UE + u];
        baseS[b * N_UE + u] = run;
        run += t;
    }
    cnt[u] = run;
}

__global__ __launch_bounds__(256) void scan_kernel(
    const int* __restrict__ cnt, int* __restrict__ offs)
{
    __shared__ int ps[256];
    __shared__ int ps2[257];
    const int t = threadIdx.x;
    const int b0 = t * (N_UE / 256);
    int s = 0;
    for (int i = 0; i < N_UE / 256; ++i) s += cnt[b0 + i];
    ps[t] = s;
    __syncthreads();
    if (t == 0) {
        int r = 0;
        for (int i = 0; i < 256; ++i) { ps2[i] = r; r += ps[i]; }
        ps2[256] = r;
    }
    __syncthreads();
    int r = ps2[t];
    for (int i = 0; i < N_UE / 256; ++i) { offs[b0 + i] = r; r += cnt[b0 + i]; }
    if (t == 255) offs[N_UE] = ps2[256];
}

__global__ __launch_bounds__(256) void scatter_src(
    const int* __restrict__ src, const int* __restrict__ dst,
    const float2* __restrict__ e0ua, const float2* __restrict__ e0au,
    const int* __restrict__ baseS, const int* __restrict__ offs,
    int2* __restrict__ sd2, float4* __restrict__ e4s, int* __restrict__ invS)
{
    __shared__ int cursor[N_UE];
    const int b = blockIdx.x;
    for (int i = threadIdx.x; i < N_UE; i += 256)
        cursor[i] = offs[i] + baseS[b * N_UE + i];
    __syncthreads();
    const int beg = b * EPSB;
    for (int e = beg + threadIdx.x; e < beg + EPSB; e += 256) {
        int s = src[e];
        int pos = atomicAdd(&cursor[s], 1);
        sd2[pos] = make_int2(s, dst[e]);
        float2 a = e0ua[e], c = e0au[e];
        e4s[pos] = make_float4(a.x, a.y, c.x, c.y);
        invS[e] = pos;
    }
}

// ---------------------------------------------------------------------------
// Fused edge pass, all-LDS inner loop.
// Phase 1 (lane=edge): stream 256-edge stage, fused edge-update, stage recs.
// Phase 2 (lane=dim, 8 groups x 32 edges): branch-free independent iterations:
//   m_ua = relu(Qua_s[sidx+dim] + e0 u0 + e1 u1) -> ds_add aggap_s[dt+dim]
//   m_au = relu(Pau_s[dt+dim]  + e2 w0 + e3 w1) -> ds_add aggue_s[sidx+dim]
// aggue_s covers NROWS contiguous src nodes (src-sorted); global fallback.
// ---------------------------------------------------------------------------
template<bool EUPD>
__global__ __launch_bounds__(256) void fused_edge(
    const int2* __restrict__ sd2, float4* __restrict__ e4s,
    const float2* __restrict__ RueA, const float2* __restrict__ RueB,
    const float2* __restrict__ RapA, const float2* __restrict__ RapB,
    const float* __restrict__ EcA, const float* __restrict__ EcB,
    const float* __restrict__ Qua, const float* __restrict__ Pau,
    const float* __restrict__ cu, const float* __restrict__ cw,
    float* __restrict__ agg_ue, float* __restrict__ partial_ap)
{
    __shared__ float aggap_s[N_AP * 32];    // 16 KB
    __shared__ float pau_s[N_AP * 32];      // 16 KB
    __shared__ float aggue_s[NROWS * 32];   // 6 KB
    __shared__ float qua_s[NROWS * 32];     // 6 KB
    __shared__ int4  recA_s[SSZ];           // 4 KB  (sidx32, dt32, e0, e1)
    __shared__ int4  recB_s[SSZ];           // 4 KB  (sidx32, dt32, e2, e3)

    const int tid = threadIdx.x;
    const int g   = tid >> 5;
    const int dim = tid & 31;
    const int base0 = blockIdx.x * CHUNK;
    const int u_lo  = sd2[base0].x;         // first (lowest) src node of block

    for (int i = tid; i < N_AP * 32; i += 256) { aggap_s[i] = 0.f; pau_s[i] = Pau[i]; }
    for (int i = tid; i < NROWS * 32; i += 256) {
        aggue_s[i] = 0.f;
        int gi = u_lo * 32 + i;
        qua_s[i] = (gi < N_UE * 32) ? Qua[gi] : 0.f;
    }

    const float u0 = cu[dim], u1 = cu[32 + dim];
    const float w0 = cw[dim], w1 = cw[32 + dim];
    float c00 = 0.f, c01 = 0.f, c10 = 0.f, c11 = 0.f;
    float d00 = 0.f, d01 = 0.f, d10 = 0.f, d11 = 0.f;
    if constexpr (EUPD) {
        c00 = EcA[0]; c01 = EcA[1]; c10 = EcA[2]; c11 = EcA[3];
        d00 = EcB[0]; d01 = EcB[1]; d10 = EcB[2]; d11 = EcB[3];
    }
    __syncthreads();

    for (int stg = 0; stg < NSTG; ++stg) {
        // ---- phase 1: lane=edge ----
        {
            const int e = base0 + stg * SSZ + tid;
            int2 sd = sd2[e];
            float4 e4 = e4s[e];
            if constexpr (EUPD) {
                float2 rA = RueA[sd.x], pA = RapA[sd.y];
                float n0 = fmaxf(rA.x + pA.x + e4.x * c00 + e4.y * c10, 0.f);
                float n1 = fmaxf(rA.y + pA.y + e4.x * c01 + e4.y * c11, 0.f);
                float2 rB = RueB[sd.x], pB = RapB[sd.y];
                float m0 = fmaxf(rB.x + pB.x + e4.z * d00 + e4.w * d10, 0.f);
                float m1 = fmaxf(rB.y + pB.y + e4.z * d01 + e4.w * d11, 0.f);
                e4 = make_float4(n0, n1, m0, m1);
                e4s[e] = e4;
            }
            int sidx = (sd.x - u_lo) * 32;
            int dt32 = sd.y * 32;
            recA_s[tid] = make_int4(sidx, dt32, __float_as_int(e4.x), __float_as_int(e4.y));
            recB_s[tid] = make_int4(sidx, dt32, __float_as_int(e4.z), __float_as_int(e4.w));
        }
        __syncthreads();
        // ---- phase 2: lane=dim, 8 groups x 32 edges, independent iters ----
        {
            const int j0 = g << 5;
            #pragma unroll 8
            for (int j = 0; j < 32; ++j) {
                int4 ra = recA_s[j0 + j];                       // broadcast b128
                float e0 = __int_as_float(ra.z), e1 = __int_as_float(ra.w);
                float q;
                if (ra.x < NROWS * 32) q = qua_s[ra.x + dim];
                else                   q = Qua[u_lo * 32 + ra.x + dim];   // rare
                float mua = fmaxf(fmaf(e0, u0, fmaf(e1, u1, q)), 0.f);
                atomicAdd(&aggap_s[ra.y + dim], mua);           // ds_add_f32

                int4 rb = recB_s[j0 + j];                       // broadcast b128
                float e2 = __int_as_float(rb.z), e3 = __int_as_float(rb.w);
                float p = pau_s[rb.y + dim];
                float mau = fmaxf(fmaf(e2, w0, fmaf(e3, w1, p)), 0.f);
                if (rb.x < NROWS * 32) atomicAdd(&aggue_s[rb.x + dim], mau);
                else atomicAdd(&agg_ue[u_lo * 32 + rb.x + dim], mau);     // rare
            }
        }
        __syncthreads();
    }

    // ---- flush aggue_s rows (coalesced row atomics) ----
    for (int i = tid; i < NROWS * 32; i += 256) {
        int gi = u_lo * 32 + i;
        float v = aggue_s[i];
        if (gi < N_UE * 32 && v != 0.f) atomicAdd(&agg_ue[gi], v);
    }
    // ---- flush aggap partials ----
    float* outp = partial_ap + (size_t)blockIdx.x * (N_AP * 32);
    for (int i = tid; i < N_AP * 32; i += 256) outp[i] = aggap_s[i];
}

// ---------------------------------------------------------------------------
// Final layer-4 edge update, original order (gather via invS).
// ---------------------------------------------------------------------------
__global__ __launch_bounds__(256) void final_edge(
    const int2* __restrict__ sd2, const float4* __restrict__ e4s,
    const int* __restrict__ invS,
    const float2* __restrict__ RueA, const float2* __restrict__ RueB,
    const float2* __restrict__ RapA, const float2* __restrict__ RapB,
    const float* __restrict__ EcA, const float* __restrict__ EcB,
    float2* __restrict__ out_eua, float2* __restrict__ out_eau)
{
    const int e = blockIdx.x * 256 + threadIdx.x;
    const int pos = invS[e];
    int2 sd = sd2[pos];
    float4 e4 = e4s[pos];
    float c00 = EcA[0], c01 = EcA[1], c10 = EcA[2], c11 = EcA[3];
    float d00 = EcB[0], d01 = EcB[1], d10 = EcB[2], d11 = EcB[3];
    float2 rA = RueA[sd.x], pA = RapA[sd.y];
    float n0 = fmaxf(rA.x + pA.x + e4.x * c00 + e4.y * c10, 0.f);
    float n1 = fmaxf(rA.y + pA.y + e4.x * c01 + e4.y * c11, 0.f);
    float2 rB = RueB[sd.x], pB = RapB[sd.y];
    float m0 = fmaxf(rB.x + pB.x + e4.z * d00 + e4.w * d10, 0.f);
    float m1 = fmaxf(rB.y + pB.y + e4.z * d01 + e4.w * d11, 0.f);
    out_eua[e] = make_float2(n0, n1);
    out_eau[e] = make_float2(m0, m1);
}

// ---------------------------------------------------------------------------
// UE node update + next-layer tables (+ power head for LAST)
// ---------------------------------------------------------------------------
template<bool FIRST, bool LAST>
__global__ __launch_bounds__(256) void node_ue_kernel(
    const float* __restrict__ x_prev, const float* __restrict__ agg_ue,
    const float* __restrict__ Wu, const float* __restrict__ bu,
    const float* __restrict__ Wm_next, const float* __restrict__ bm_next,
    const float* __restrict__ WeUa, const float* __restrict__ WeUb,
    const float* __restrict__ Wp1, const float* __restrict__ bp1,
    const float* __restrict__ Wp2, const float* __restrict__ bp2,
    float* __restrict__ x_new, float* __restrict__ Qua_next,
    float2* __restrict__ RueA, float2* __restrict__ RueB,
    float2* __restrict__ ue_out)
{
    constexpr int KIN = FIRST ? 33 : 64;
    __shared__ float Wu_s[64 * 32];
    __shared__ float Wm_s[32 * 32];
    __shared__ float WeA_s[64], WeB_s[64];
    __shared__ float bu_s[32], bm_s[32];
    __shared__ float Wp1_s[32 * 16], bp1_s[16], Wp2_s[16];

    const int tid = threadIdx.x;
    for (int i = tid; i < KIN * 32; i += 256) Wu_s[i] = Wu[i];
    if (tid < 32) bu_s[tid] = bu[tid];
    if (!LAST) {
        for (int i = tid; i < 1024; i += 256) Wm_s[i] = Wm_next[i];
        if (tid < 32) bm_s[tid] = bm_next[tid];
    }
    if (tid < 64) { WeA_s[tid] = WeUa[tid]; WeB_s[tid] = WeUb[tid]; }
    if (LAST) {
        for (int i = tid; i < 512; i += 256) Wp1_s[i] = Wp1[i];
        if (tid < 16) { bp1_s[tid] = bp1[tid]; Wp2_s[tid] = Wp2[tid]; }
    }
    __syncthreads();

    const int u = blockIdx.x * 256 + tid;
    float in[KIN];
    if (FIRST) {
        in[0] = x_prev[u];
        #pragma unroll
        for (int k = 0; k < 32; ++k) in[1 + k] = agg_ue[u * 32 + k];
    } else {
        #pragma unroll
        for (int k = 0; k < 32; ++k) in[k] = x_prev[u * 32 + k];
        #pragma unroll
        for (int k = 0; k < 32; ++k) in[32 + k] = agg_ue[u * 32 + k];
    }
    float out[32];
    #pragma unroll
    for (int d = 0; d < 32; ++d) {
        float acc = bu_s[d];
        #pragma unroll
        for (int k = 0; k < KIN; ++k) acc = fmaf(in[k], Wu_s[k * 32 + d], acc);
        out[d] = fmaxf(acc, 0.f);
    }
    #pragma unroll
    for (int d = 0; d < 32; ++d) x_new[u * 32 + d] = out[d];
    if (!LAST) {
        #pragma unroll
        for (int d = 0; d < 32; ++d) {
            float acc = bm_s[d];
            #pragma unroll
            for (int k = 0; k < 32; ++k) acc = fmaf(out[k], Wm_s[k * 32 + d], acc);
            Qua_next[u * 32 + d] = acc;
        }
    }
    float r0 = 0.f, r1 = 0.f, s0 = 0.f, s1 = 0.f;
    #pragma unroll
    for (int k = 0; k < 32; ++k) {
        r0 = fmaf(out[k], WeA_s[k * 2],     r0);
        r1 = fmaf(out[k], WeA_s[k * 2 + 1], r1);
        s0 = fmaf(out[k], WeB_s[k * 2],     s0);
        s1 = fmaf(out[k], WeB_s[k * 2 + 1], s1);
    }
    RueA[u] = make_float2(r0, r1);
    RueB[u] = make_float2(s0, s1);
    if (LAST) {
        float z = bp2[0];
        #pragma unroll
        for (int j = 0; j < 16; ++j) {
            float h = bp1_s[j];
            #pragma unroll
            for (int k = 0; k < 32; ++k) h = fmaf(out[k], Wp1_s[k * 16 + j], h);
            z = fmaf(fmaxf(h, 0.f), Wp2_s[j], z);
        }
        float pw = 1.f / (1.f + expf(-z));
        ue_out[u] = make_float2(out[0], pw);
    }
}

// ---------------------------------------------------------------------------
// AP: reduce partials -> agg_ap, node update, next-layer tables
// ---------------------------------------------------------------------------
template<bool FIRST, bool LAST>
__global__ __launch_bounds__(256) void node_ap_kernel(
    const float* __restrict__ partial,
    const float* __restrict__ x_prev,
    const float* __restrict__ Wu, const float* __restrict__ bu,
    const float* __restrict__ Wm_next, const float* __restrict__ bm_next,
    const float* __restrict__ WeA, const float* __restrict__ beA,
    const float* __restrict__ WeB, const float* __restrict__ beB,
    float* __restrict__ x_new, float* __restrict__ Pau_next,
    float2* __restrict__ RapA, float2* __restrict__ RapB)
{
    __shared__ float red[256];
    __shared__ float agg_s[32];
    __shared__ float xnew_s[32];
    const int a = blockIdx.x, tid = threadIdx.x;
    const int d = tid & 31, p0 = tid >> 5;
    float acc = 0.f;
    for (int p = p0; p < NPART; p += 8)
        acc += partial[(size_t)p * (N_AP * 32) + a * 32 + d];
    red[tid] = acc;
    __syncthreads();
    if (tid < 32) {
        float s = 0.f;
        #pragma unroll
        for (int i = 0; i < 8; ++i) s += red[i * 32 + tid];
        agg_s[tid] = s;
    }
    __syncthreads();
    if (tid < 32) {
        float acc2 = bu[d];
        if (FIRST) {
            #pragma unroll
            for (int k = 0; k < 32; ++k) acc2 = fmaf(agg_s[k], Wu[k * 32 + d], acc2);
        } else {
            #pragma unroll
            for (int k = 0; k < 32; ++k) acc2 = fmaf(x_prev[a * 32 + k], Wu[k * 32 + d], acc2);
            #pragma unroll
            for (int k = 0; k < 32; ++k) acc2 = fmaf(agg_s[k], Wu[(32 + k) * 32 + d], acc2);
        }
        float xn = fmaxf(acc2, 0.f);
        xnew_s[d] = xn;
        x_new[a * 32 + d] = xn;
    }
    __syncthreads();
    if (!LAST) {
        if (tid < 32) {
            float acc3 = bm_next[d];
            #pragma unroll
            for (int k = 0; k < 32; ++k) acc3 = fmaf(xnew_s[k], Wm_next[k * 32 + d], acc3);
            Pau_next[a * 32 + d] = acc3;
        }
    }
    if (tid == 0) {
        float q0 = beA[0], q1 = beA[1], t0 = beB[0], t1 = beB[1];
        #pragma unroll
        for (int k = 0; k < 32; ++k) {
            q0 = fmaf(xnew_s[k], WeA[k * 2],     q0);
            q1 = fmaf(xnew_s[k], WeA[k * 2 + 1], q1);
            t0 = fmaf(xnew_s[k], WeB[k * 2],     t0);
            t1 = fmaf(xnew_s[k], WeB[k * 2 + 1], t1);
        }
        RapA[a] = make_float2(q0, q1);
        RapB[a] = make_float2(t0, t1);
    }
}

// ---------------------------------------------------------------------------
extern "C" void kernel_launch(void* const* d_in, const int* in_sizes, int n_in,
                              void* d_out_v, int out_size, void* d_ws, size_t ws_size,
                              hipStream_t stream)
{
    const float*  x_ue   = (const float*)d_in[0];
    const float2* e0ua   = (const float2*)d_in[1];
    const float2* e0au   = (const float2*)d_in[2];
    const int*    src    = (const int*)d_in[3];
    const int*    dst    = (const int*)d_in[4];
    const float* Wm1_ua = (const float*)d_in[5];
    const float* bm1_ua = (const float*)d_in[6];
    const float* Wm1_au = (const float*)d_in[7];
    const float* bm1_au = (const float*)d_in[8];
    const float* Wu1_ap = (const float*)d_in[9];
    const float* bu1_ap = (const float*)d_in[10];
    const float* Wu1_ue = (const float*)d_in[11];
    const float* bu1_ue = (const float*)d_in[12];
    const float* We1_ua = (const float*)d_in[13];
    const float* be1_ua = (const float*)d_in[14];
    const float* We1_au = (const float*)d_in[15];
    const float* be1_au = (const float*)d_in[16];
    const float* Wm_ua  = (const float*)d_in[17];
    const float* bm_ua  = (const float*)d_in[18];
    const float* Wm_au  = (const float*)d_in[19];
    const float* bm_au  = (const float*)d_in[20];
    const float* Wu_ap  = (const float*)d_in[21];
    const float* bu_ap  = (const float*)d_in[22];
    const float* Wu_ue  = (const float*)d_in[23];
    const float* bu_ue  = (const float*)d_in[24];
    const float* We_ua  = (const float*)d_in[25];
    const float* be_ua  = (const float*)d_in[26];
    const float* We_au  = (const float*)d_in[27];
    const float* be_au  = (const float*)d_in[28];
    const float* Wp1    = (const float*)d_in[29];
    const float* bp1    = (const float*)d_in[30];
    const float* Wp2    = (const float*)d_in[31];
    const float* bp2    = (const float*)d_in[32];

    float*  outp    = (float*)d_out_v;
    float2* out_ue  = (float2*)outp;                              // [16384][2]
    float*  out_ap  = outp + N_UE * 2;                            // [128][32]
    float2* out_eua = (float2*)(outp + N_UE * 2 + N_AP * 32);     // [E][2]
    float2* out_eau = (float2*)(outp + N_UE * 2 + N_AP * 32 + (size_t)NE * 2);

    float* ws = (float*)d_ws;
    float* x_ueA  = ws;          ws += N_UE * 32;
    float* x_ueB  = ws;          ws += N_UE * 32;
    float* x_apA  = ws;          ws += N_AP * 32;
    float* x_apB  = ws;          ws += N_AP * 32;
    float* agg_ue = ws;          ws += N_UE * 32;
    float* Qua    = ws;          ws += N_UE * 32;
    float* Pau    = ws;          ws += N_AP * 32;
    float2* RueA  = (float2*)ws; ws += N_UE * 2;
    float2* RueB  = (float2*)ws; ws += N_UE * 2;
    float2* RapA  = (float2*)ws; ws += N_AP * 2;
    float2* RapB  = (float2*)ws; ws += N_AP * 2;
    float* partial = ws;         ws += (size_t)NPART * N_AP * 32; // 16 MB
    int* baseS     = (int*)partial;                               // alias: [NSB][N_UE] = 16 MB
    int* cnt   = (int*)ws;       ws += N_UE;
    int* offs  = (int*)ws;       ws += N_UE + 4;
    int* invS  = (int*)ws;       ws += NE;                        // 8 MB
    int2* sd2  = (int2*)ws;      ws += (size_t)NE * 2;            // 16 MB
    float4* e4s = (float4*)ws;   ws += (size_t)NE * 4;            // 32 MB
    int* histS = (int*)e4s;      // alias: 16 MB, dead before e4s written

    dim3 blk(256);
    const size_t aggBytes = (size_t)N_UE * 32 * sizeof(float);

    // ---- src-sort ----
    hist_src<<<NSB, blk, 0, stream>>>(src, histS);
    colscan_kernel<<<N_UE / 256, blk, 0, stream>>>(histS, baseS, cnt);
    scan_kernel<<<1, blk, 0, stream>>>(cnt, offs);
    scatter_src<<<NSB, blk, 0, stream>>>(src, dst, e0ua, e0au, baseS, offs,
                                         sd2, e4s, invS);

    init_kernel<<<N_UE * 32 / 256, blk, 0, stream>>>(x_ue, Wm1_ua, bm1_ua, bm1_au, Qua, Pau);

    // ---- layer 1 ----
    hipMemsetAsync(agg_ue, 0, aggBytes, stream);
    fused_edge<false><<<EB, blk, 0, stream>>>(
        sd2, e4s, nullptr, nullptr, nullptr, nullptr, nullptr, nullptr,
        Qua, Pau, Wm1_ua + 32, Wm1_au, agg_ue, partial);
    node_ue_kernel<true, false><<<N_UE / 256, blk, 0, stream>>>(
        x_ue, agg_ue, Wu1_ue, bu1_ue, Wm_ua, bm_ua, We1_ua, We1_au,
        nullptr, nullptr, nullptr, nullptr,
        x_ueA, Qua, RueA, RueB, nullptr);
    node_ap_kernel<true, false><<<N_AP, blk, 0, stream>>>(
        partial, nullptr, Wu1_ap, bu1_ap, Wm_au, bm_au,
        We1_ua + 64, be1_ua, We1_au + 64, be1_au,
        x_apA, Pau, RapA, RapB);

    // ---- layer 2 (edge-update 1 fused) ----
    hipMemsetAsync(agg_ue, 0, aggBytes, stream);
    fused_edge<true><<<EB, blk, 0, stream>>>(
        sd2, e4s, RueA, RueB, RapA, RapB, We1_ua + 128, We1_au + 128,
        Qua, Pau, Wm_ua + 1024, Wm_au + 1024, agg_ue, partial);
    node_ue_kernel<false, false><<<N_UE / 256, blk, 0, stream>>>(
        x_ueA, agg_ue, Wu_ue, bu_ue, Wm_ua + 1088, bm_ua + 32, We_ua, We_au,
        nullptr, nullptr, nullptr, nullptr,
        x_ueB, Qua, RueA, RueB, nullptr);
    node_ap_kernel<false, false><<<N_AP, blk, 0, stream>>>(
        partial, x_apA, Wu_ap, bu_ap, Wm_au + 1088, bm_au + 32,
        We_ua + 64, be_ua, We_au + 64, be_au,
        x_apB, Pau, RapA, RapB);

    // ---- layer 3 (edge-update 2 fused) ----
    hipMemsetAsync(agg_ue, 0, aggBytes, stream);
    fused_edge<true><<<EB, blk, 0, stream>>>(
        sd2, e4s, RueA, RueB, RapA, RapB, We_ua + 128, We_au + 128,
        Qua, Pau, Wm_ua + 2112, Wm_au + 2112, agg_ue, partial);
    node_ue_kernel<false, false><<<N_UE / 256, blk, 0, stream>>>(
        x_ueB, agg_ue, Wu_ue + 2048, bu_ue + 32, Wm_ua + 2176, bm_ua + 64,
        We_ua + 132, We_au + 132,
        nullptr, nullptr, nullptr, nullptr,
        x_ueA, Qua, RueA, RueB, nullptr);
    node_ap_kernel<false, false><<<N_AP, blk, 0, stream>>>(
        partial, x_apB, Wu_ap + 2048, bu_ap + 32, Wm_au + 2176, bm_au + 64,
        We_ua + 196, be_ua + 2, We_au + 196, be_au + 2,
        x_apA, Pau, RapA, RapB);

    // ---- layer 4 (edge-update 3 fused) ----
    hipMemsetAsync(agg_ue, 0, aggBytes, stream);
    fused_edge<true><<<EB, blk, 0, stream>>>(
        sd2, e4s, RueA, RueB, RapA, RapB, We_ua + 260, We_au + 260,
        Qua, Pau, Wm_ua + 3200, Wm_au + 3200, agg_ue, partial);
    node_ue_kernel<false, true><<<N_UE / 256, blk, 0, stream>>>(
        x_ueA, agg_ue, Wu_ue + 4096, bu_ue + 64, nullptr, nullptr,
        We_ua + 264, We_au + 264,
        Wp1, bp1, Wp2, bp2,
        x_ueB, nullptr, RueA, RueB, out_ue);
    node_ap_kernel<false, true><<<N_AP, blk, 0, stream>>>(
        partial, x_apA, Wu_ap + 4096, bu_ap + 64, nullptr, nullptr,
        We_ua + 328, be_ua + 4, We_au + 328, be_au + 4,
        out_ap, nullptr, RapA, RapB);

    // ---- final edge update (layer 4), original order ----
    final_edge<<<NE / 256, blk, 0, stream>>>(
        sd2, e4s, invS, RueA, RueB, RapA, RapB,
        We_ua + 392, We_au + 392, out_eua, out_eau);
}

// Round 7
// 1106.228 us; speedup vs baseline: 3.4765x; 3.4765x over previous
//
#include <hip/hip_runtime.h>
#include <math.h>

#define N_UE 16384
#define N_AP 128
#define NE   2097152
#define NSB  256               // sort blocks
#define EPSB (NE / NSB)        // 8192 edges per sort block
#define APCH 128               // chunks per AP node
#define NPART (N_AP * APCH)    // 16384 ap partials

// ---------------------------------------------------------------------------
// init: Qua1[u][d] = x_ue[u]*Wm1_ua[0][d] + bm1_ua[d];  Pau1[a][d] = bm1_au[d]
// ---------------------------------------------------------------------------
__global__ __launch_bounds__(256) void init_kernel(
    const float* __restrict__ x_ue, const float* __restrict__ Wm1_ua,
    const float* __restrict__ bm1_ua, const float* __restrict__ bm1_au,
    float* __restrict__ Qua, float* __restrict__ Pau)
{
    int i = blockIdx.x * 256 + threadIdx.x;
    int d = i & 31;
    Qua[i] = fmaf(x_ue[i >> 5], Wm1_ua[d], bm1_ua[d]);
    if (i < N_AP * 32) Pau[i] = bm1_au[d];
}

// ---------------------------------------------------------------------------
// src-sort: histogram -> column scan -> prefix scan -> scatter
// ---------------------------------------------------------------------------
__global__ __launch_bounds__(256) void hist_src(
    const int* __restrict__ src, int* __restrict__ histS)
{
    __shared__ int h[N_UE];
    for (int i = threadIdx.x; i < N_UE; i += 256) h[i] = 0;
    __syncthreads();
    const int beg = blockIdx.x * EPSB;
    for (int e = beg + threadIdx.x; e < beg + EPSB; e += 256)
        atomicAdd(&h[src[e]], 1);
    __syncthreads();
    for (int i = threadIdx.x; i < N_UE; i += 256) histS[blockIdx.x * N_UE + i] = h[i];
}

__global__ __launch_bounds__(256) void colscan_kernel(
    const int* __restrict__ histS, int* __restrict__ baseS, int* __restrict__ cnt)
{
    const int u = blockIdx.x * 256 + threadIdx.x;
    int run = 0;
    for (int b = 0; b < NSB; ++b) {
        int t = histS[b * N_UE + u];
        baseS[b * N_UE + u] = run;
        run += t;
    }
    cnt[u] = run;
}

__global__ __launch_bounds__(256) void scan_kernel(
    const int* __restrict__ cnt, int* __restrict__ offs)
{
    __shared__ int ps[256];
    __shared__ int ps2[257];
    const int t = threadIdx.x;
    const int b0 = t * (N_UE / 256);
    int s = 0;
    for (int i = 0; i < N_UE / 256; ++i) s += cnt[b0 + i];
    ps[t] = s;
    __syncthreads();
    if (t == 0) {
        int r = 0;
        for (int i = 0; i < 256; ++i) { ps2[i] = r; r += ps[i]; }
        ps2[256] = r;
    }
    __syncthreads();
    int r = ps2[t];
    for (int i = 0; i < N_UE / 256; ++i) { offs[b0 + i] = r; r += cnt[b0 + i]; }
    if (t == 255) offs[N_UE] = ps2[256];
}

__global__ __launch_bounds__(256) void scatter_src(
    const int* __restrict__ src, const int* __restrict__ dst,
    const float2* __restrict__ e0au,
    const int* __restrict__ baseS, const int* __restrict__ offs,
    int* __restrict__ dtS, float2* __restrict__ attS, int* __restrict__ invS)
{
    __shared__ int cursor[N_UE];
    const int b = blockIdx.x;
    for (int i = threadIdx.x; i < N_UE; i += 256)
        cursor[i] = offs[i] + baseS[b * N_UE + i];
    __syncthreads();
    const int beg = b * EPSB;
    for (int e = beg + threadIdx.x; e < beg + EPSB; e += 256) {
        int s = src[e];
        int pos = atomicAdd(&cursor[s], 1);
        dtS[pos] = dst[e];
        attS[pos] = e0au[e];
        invS[e] = pos;
    }
}

// ---------------------------------------------------------------------------
// dst-sort (128 bins)
// ---------------------------------------------------------------------------
__global__ __launch_bounds__(256) void hist_dst(
    const int* __restrict__ dst, int* __restrict__ histD)
{
    __shared__ int h[N_AP];
    if (threadIdx.x < N_AP) h[threadIdx.x] = 0;
    __syncthreads();
    const int beg = blockIdx.x * EPSB;
    for (int e = beg + threadIdx.x; e < beg + EPSB; e += 256)
        atomicAdd(&h[dst[e]], 1);
    __syncthreads();
    if (threadIdx.x < N_AP) histD[blockIdx.x * N_AP + threadIdx.x] = h[threadIdx.x];
}

__global__ __launch_bounds__(128) void scan_dst(
    const int* __restrict__ histD, int* __restrict__ offsD, int* __restrict__ offsDnode)
{
    __shared__ int colTot[N_AP], colStart[N_AP];
    const int a = threadIdx.x;
    int run = 0;
    for (int b = 0; b < NSB; ++b) {
        offsD[b * N_AP + a] = run;
        run += histD[b * N_AP + a];
    }
    colTot[a] = run;
    __syncthreads();
    if (a == 0) {
        int r = 0;
        for (int i = 0; i < N_AP; ++i) { colStart[i] = r; r += colTot[i]; }
    }
    __syncthreads();
    const int st = colStart[a];
    offsDnode[a] = st;
    if (a == 0) offsDnode[N_AP] = NE;
    for (int b = 0; b < NSB; ++b) offsD[b * N_AP + a] += st;
}

__global__ __launch_bounds__(256) void scatter_dst(
    const int* __restrict__ src, const int* __restrict__ dst,
    const float2* __restrict__ e0ua, const int* __restrict__ offsD,
    int* __restrict__ srcD, float2* __restrict__ attD, int* __restrict__ invD)
{
    __shared__ int cursor[N_AP];
    const int b = blockIdx.x;
    if (threadIdx.x < N_AP) cursor[threadIdx.x] = offsD[b * N_AP + threadIdx.x];
    __syncthreads();
    const int beg = b * EPSB;
    for (int e = beg + threadIdx.x; e < beg + EPSB; e += 256) {
        int dt = dst[e];
        int pos = atomicAdd(&cursor[dt], 1);
        srcD[pos] = src[e];
        attD[pos] = e0ua[e];
        invD[e] = pos;
    }
}

// ---------------------------------------------------------------------------
// UE pass: one 32-lane group per UE node (src-CSR). lane = dim.
// EUPD e_au: relu(RueB[u] + RapB[dt] + e_au @ EcB)  (redundant in all lanes,
//            lane 0 stores). m_au = relu(Pau[dt] + e·w) -> register acc ->
//            ONE coalesced agg_ue row store. No atomics, no LDS.
// ---------------------------------------------------------------------------
template<bool EUPD>
__global__ __launch_bounds__(256) void ue_pass(
    const int* __restrict__ offs, const int* __restrict__ dtS,
    const float2* __restrict__ attIn, float2* __restrict__ attOut,
    const float2* __restrict__ RueB, const float2* __restrict__ RapB,
    const float* __restrict__ EcB,
    const float* __restrict__ Pau, const float* __restrict__ cw,
    float* __restrict__ agg_ue)
{
    const int tid = threadIdx.x;
    const int u   = blockIdx.x * 8 + (tid >> 5);
    const int dim = tid & 31;

    const float w0 = cw[dim], w1 = cw[32 + dim];
    float d00 = 0.f, d01 = 0.f, d10 = 0.f, d11 = 0.f, rbx = 0.f, rby = 0.f;
    if constexpr (EUPD) {
        d00 = EcB[0]; d01 = EcB[1]; d10 = EcB[2]; d11 = EcB[3];
        float2 r = RueB[u]; rbx = r.x; rby = r.y;
    }

    const int e0 = offs[u], e1 = offs[u + 1];
    float acc = 0.f;
    #pragma unroll 4
    for (int e = e0; e < e1; ++e) {
        int dt = dtS[e];                       // broadcast (group-uniform)
        float2 ea = attIn[e];                  // broadcast 8B
        if constexpr (EUPD) {
            float2 rp = RapB[dt];              // broadcast 8B, L1 (1KB)
            float m0 = fmaxf(rbx + rp.x + ea.x * d00 + ea.y * d10, 0.f);
            float m1 = fmaxf(rby + rp.y + ea.x * d01 + ea.y * d11, 0.f);
            ea = make_float2(m0, m1);
            if (dim == 0) attOut[e] = ea;      // 1 lane, 8B
        }
        float p = Pau[dt * 32 + dim];          // coalesced 128B row, L1 (16KB)
        acc += fmaxf(fmaf(ea.x, w0, fmaf(ea.y, w1, p)), 0.f);
    }
    agg_ue[u * 32 + dim] = acc;                // exclusive owner: plain store
}

// ---------------------------------------------------------------------------
// AP pass: one 32-lane group per AP-node chunk (dst-CSR). lane = dim.
// EUPD e_ua: relu(RueA[s] + RapA[a] + e_ua @ EcA). m_ua = relu(Qua[s] + e·u)
// -> register acc -> partial[gid] plain store. No atomics, no LDS.
// ---------------------------------------------------------------------------
template<bool EUPD>
__global__ __launch_bounds__(256) void ap_pass(
    const int* __restrict__ offsDnode, const int* __restrict__ srcD,
    const float2* __restrict__ attIn, float2* __restrict__ attOut,
    const float2* __restrict__ RueA, const float2* __restrict__ RapA,
    const float* __restrict__ EcA,
    const float* __restrict__ Qua, const float* __restrict__ cu,
    float* __restrict__ partial)
{
    const int tid = threadIdx.x;
    const int gid = blockIdx.x * 8 + (tid >> 5);
    const int dim = tid & 31;
    const int a   = gid >> 7;        // APCH=128 chunks per node
    const int c   = gid & 127;

    const float u0 = cu[dim], u1 = cu[32 + dim];
    float c00 = 0.f, c01 = 0.f, c10 = 0.f, c11 = 0.f, rax = 0.f, ray = 0.f;
    if constexpr (EUPD) {
        c00 = EcA[0]; c01 = EcA[1]; c10 = EcA[2]; c11 = EcA[3];
        float2 r = RapA[a]; rax = r.x; ray = r.y;
    }

    const int s0 = offsDnode[a], s1 = offsDnode[a + 1];
    const int len = s1 - s0;
    const int b0 = s0 + (int)(((long long)len * c) >> 7);
    const int b1 = s0 + (int)(((long long)len * (c + 1)) >> 7);

    float acc = 0.f;
    #pragma unroll 4
    for (int e = b0; e < b1; ++e) {
        int s = srcD[e];                       // broadcast
        float2 ea = attIn[e];                  // broadcast 8B
        if constexpr (EUPD) {
            float2 ru = RueA[s];               // broadcast 8B, L2 (128KB)
            float n0 = fmaxf(rax + ru.x + ea.x * c00 + ea.y * c10, 0.f);
            float n1 = fmaxf(ray + ru.y + ea.x * c01 + ea.y * c11, 0.f);
            ea = make_float2(n0, n1);
            if (dim == 0) attOut[e] = ea;
        }
        float q = Qua[s * 32 + dim];           // coalesced 128B row, L2 (2MB)
        acc += fmaxf(fmaf(ea.x, u0, fmaf(ea.y, u1, q)), 0.f);
    }
    partial[gid * 32 + dim] = acc;             // exclusive owner: plain store
}

// ---------------------------------------------------------------------------
// Final layer-4 edge update, original order (gather via invS/invD).
// ---------------------------------------------------------------------------
__global__ __launch_bounds__(256) void final_edge(
    const int* __restrict__ src, const int* __restrict__ dst,
    const int* __restrict__ invS, const int* __restrict__ invD,
    const float2* __restrict__ attS, const float2* __restrict__ attD,
    const float2* __restrict__ RueA, const float2* __restrict__ RueB,
    const float2* __restrict__ RapA, const float2* __restrict__ RapB,
    const float* __restrict__ EcA, const float* __restrict__ EcB,
    float2* __restrict__ out_eua, float2* __restrict__ out_eau)
{
    const int e = blockIdx.x * 256 + threadIdx.x;
    const int s = src[e], dt = dst[e];
    float c00 = EcA[0], c01 = EcA[1], c10 = EcA[2], c11 = EcA[3];
    float d00 = EcB[0], d01 = EcB[1], d10 = EcB[2], d11 = EcB[3];
    float2 eua = attD[invD[e]];
    float2 eau = attS[invS[e]];
    float2 rA = RueA[s], pA = RapA[dt];
    float n0 = fmaxf(rA.x + pA.x + eua.x * c00 + eua.y * c10, 0.f);
    float n1 = fmaxf(rA.y + pA.y + eua.x * c01 + eua.y * c11, 0.f);
    float2 rB = RueB[s], pB = RapB[dt];
    float m0 = fmaxf(rB.x + pB.x + eau.x * d00 + eau.y * d10, 0.f);
    float m1 = fmaxf(rB.y + pB.y + eau.x * d01 + eau.y * d11, 0.f);
    out_eua[e] = make_float2(n0, n1);
    out_eau[e] = make_float2(m0, m1);
}

// ---------------------------------------------------------------------------
// UE node update + next-layer tables (+ power head for LAST)
// ---------------------------------------------------------------------------
template<bool FIRST, bool LAST>
__global__ __launch_bounds__(256) void node_ue_kernel(
    const float* __restrict__ x_prev, const float* __restrict__ agg_ue,
    const float* __restrict__ Wu, const float* __restrict__ bu,
    const float* __restrict__ Wm_next, const float* __restrict__ bm_next,
    const float* __restrict__ WeUa, const float* __restrict__ WeUb,
    const float* __restrict__ Wp1, const float* __restrict__ bp1,
    const float* __restrict__ Wp2, const float* __restrict__ bp2,
    float* __restrict__ x_new, float* __restrict__ Qua_next,
    float2* __restrict__ RueA, float2* __restrict__ RueB,
    float2* __restrict__ ue_out)
{
    constexpr int KIN = FIRST ? 33 : 64;
    __shared__ float Wu_s[64 * 32];
    __shared__ float Wm_s[32 * 32];
    __shared__ float WeA_s[64], WeB_s[64];
    __shared__ float bu_s[32], bm_s[32];
    __shared__ float Wp1_s[32 * 16], bp1_s[16], Wp2_s[16];

    const int tid = threadIdx.x;
    for (int i = tid; i < KIN * 32; i += 256) Wu_s[i] = Wu[i];
    if (tid < 32) bu_s[tid] = bu[tid];
    if (!LAST) {
        for (int i = tid; i < 1024; i += 256) Wm_s[i] = Wm_next[i];
        if (tid < 32) bm_s[tid] = bm_next[tid];
    }
    if (tid < 64) { WeA_s[tid] = WeUa[tid]; WeB_s[tid] = WeUb[tid]; }
    if (LAST) {
        for (int i = tid; i < 512; i += 256) Wp1_s[i] = Wp1[i];
        if (tid < 16) { bp1_s[tid] = bp1[tid]; Wp2_s[tid] = Wp2[tid]; }
    }
    __syncthreads();

    const int u = blockIdx.x * 256 + tid;
    float in[KIN];
    if (FIRST) {
        in[0] = x_prev[u];
        #pragma unroll
        for (int k = 0; k < 32; ++k) in[1 + k] = agg_ue[u * 32 + k];
    } else {
        #pragma unroll
        for (int k = 0; k < 32; ++k) in[k] = x_prev[u * 32 + k];
        #pragma unroll
        for (int k = 0; k < 32; ++k) in[32 + k] = agg_ue[u * 32 + k];
    }
    float out[32];
    #pragma unroll
    for (int d = 0; d < 32; ++d) {
        float acc = bu_s[d];
        #pragma unroll
        for (int k = 0; k < KIN; ++k) acc = fmaf(in[k], Wu_s[k * 32 + d], acc);
        out[d] = fmaxf(acc, 0.f);
    }
    #pragma unroll
    for (int d = 0; d < 32; ++d) x_new[u * 32 + d] = out[d];
    if (!LAST) {
        #pragma unroll
        for (int d = 0; d < 32; ++d) {
            float acc = bm_s[d];
            #pragma unroll
            for (int k = 0; k < 32; ++k) acc = fmaf(out[k], Wm_s[k * 32 + d], acc);
            Qua_next[u * 32 + d] = acc;
        }
    }
    float r0 = 0.f, r1 = 0.f, s0 = 0.f, s1 = 0.f;
    #pragma unroll
    for (int k = 0; k < 32; ++k) {
        r0 = fmaf(out[k], WeA_s[k * 2],     r0);
        r1 = fmaf(out[k], WeA_s[k * 2 + 1], r1);
        s0 = fmaf(out[k], WeB_s[k * 2],     s0);
        s1 = fmaf(out[k], WeB_s[k * 2 + 1], s1);
    }
    RueA[u] = make_float2(r0, r1);
    RueB[u] = make_float2(s0, s1);
    if (LAST) {
        float z = bp2[0];
        #pragma unroll
        for (int j = 0; j < 16; ++j) {
            float h = bp1_s[j];
            #pragma unroll
            for (int k = 0; k < 32; ++k) h = fmaf(out[k], Wp1_s[k * 16 + j], h);
            z = fmaf(fmaxf(h, 0.f), Wp2_s[j], z);
        }
        float pw = 1.f / (1.f + expf(-z));
        ue_out[u] = make_float2(out[0], pw);
    }
}

// ---------------------------------------------------------------------------
// AP: reduce per-chunk partials -> agg_ap, node update, next-layer tables
// ---------------------------------------------------------------------------
template<bool FIRST, bool LAST>
__global__ __launch_bounds__(256) void node_ap_kernel(
    const float* __restrict__ partial,
    const float* __restrict__ x_prev,
    const float* __restrict__ Wu, const float* __restrict__ bu,
    const float* __restrict__ Wm_next, const float* __restrict__ bm_next,
    const float* __restrict__ WeA, const float* __restrict__ beA,
    const float* __restrict__ WeB, const float* __restrict__ beB,
    float* __restrict__ x_new, float* __restrict__ Pau_next,
    float2* __restrict__ RapA, float2* __restrict__ RapB)
{
    __shared__ float red[256];
    __shared__ float agg_s[32];
    __shared__ float xnew_s[32];
    const int a = blockIdx.x, tid = threadIdx.x;
    const int d = tid & 31, p0 = tid >> 5;
    float acc = 0.f;
    for (int p = p0; p < APCH; p += 8)
        acc += partial[(size_t)(a * APCH + p) * 32 + d];
    red[tid] = acc;
    __syncthreads();
    if (tid < 32) {
        float s = 0.f;
        #pragma unroll
        for (int i = 0; i < 8; ++i) s += red[i * 32 + tid];
        agg_s[tid] = s;
    }
    __syncthreads();
    if (tid < 32) {
        float acc2 = bu[d];
        if (FIRST) {
            #pragma unroll
            for (int k = 0; k < 32; ++k) acc2 = fmaf(agg_s[k], Wu[k * 32 + d], acc2);
        } else {
            #pragma unroll
            for (int k = 0; k < 32; ++k) acc2 = fmaf(x_prev[a * 32 + k], Wu[k * 32 + d], acc2);
            #pragma unroll
            for (int k = 0; k < 32; ++k) acc2 = fmaf(agg_s[k], Wu[(32 + k) * 32 + d], acc2);
        }
        float xn = fmaxf(acc2, 0.f);
        xnew_s[d] = xn;
        x_new[a * 32 + d] = xn;
    }
    __syncthreads();
    if (!LAST) {
        if (tid < 32) {
            float acc3 = bm_next[d];
            #pragma unroll
            for (int k = 0; k < 32; ++k) acc3 = fmaf(xnew_s[k], Wm_next[k * 32 + d], acc3);
            Pau_next[a * 32 + d] = acc3;
        }
    }
    if (tid == 0) {
        float q0 = beA[0], q1 = beA[1], t0 = beB[0], t1 = beB[1];
        #pragma unroll
        for (int k = 0; k < 32; ++k) {
            q0 = fmaf(xnew_s[k], WeA[k * 2],     q0);
            q1 = fmaf(xnew_s[k], WeA[k * 2 + 1], q1);
            t0 = fmaf(xnew_s[k], WeB[k * 2],     t0);
            t1 = fmaf(xnew_s[k], WeB[k * 2 + 1], t1);
        }
        RapA[a] = make_float2(q0, q1);
        RapB[a] = make_float2(t0, t1);
    }
}

// ---------------------------------------------------------------------------
extern "C" void kernel_launch(void* const* d_in, const int* in_sizes, int n_in,
                              void* d_out_v, int out_size, void* d_ws, size_t ws_size,
                              hipStream_t stream)
{
    const float*  x_ue   = (const float*)d_in[0];
    const float2* e0ua   = (const float2*)d_in[1];
    const float2* e0au   = (const float2*)d_in[2];
    const int*    src    = (const int*)d_in[3];
    const int*    dst    = (const int*)d_in[4];
    const float* Wm1_ua = (const float*)d_in[5];
    const float* bm1_ua = (const float*)d_in[6];
    const float* Wm1_au = (const float*)d_in[7];
    const float* bm1_au = (const float*)d_in[8];
    const float* Wu1_ap = (const float*)d_in[9];
    const float* bu1_ap = (const float*)d_in[10];
    const float* Wu1_ue = (const float*)d_in[11];
    const float* bu1_ue = (const float*)d_in[12];
    const float* We1_ua = (const float*)d_in[13];
    const float* be1_ua = (const float*)d_in[14];
    const float* We1_au = (const float*)d_in[15];
    const float* be1_au = (const float*)d_in[16];
    const float* Wm_ua  = (const float*)d_in[17];
    const float* bm_ua  = (const float*)d_in[18];
    const float* Wm_au  = (const float*)d_in[19];
    const float* bm_au  = (const float*)d_in[20];
    const float* Wu_ap  = (const float*)d_in[21];
    const float* bu_ap  = (const float*)d_in[22];
    const float* Wu_ue  = (const float*)d_in[23];
    const float* bu_ue  = (const float*)d_in[24];
    const float* We_ua  = (const float*)d_in[25];
    const float* be_ua  = (const float*)d_in[26];
    const float* We_au  = (const float*)d_in[27];
    const float* be_au  = (const float*)d_in[28];
    const float* Wp1    = (const float*)d_in[29];
    const float* bp1    = (const float*)d_in[30];
    const float* Wp2    = (const float*)d_in[31];
    const float* bp2    = (const float*)d_in[32];

    float*  outp    = (float*)d_out_v;
    float2* out_ue  = (float2*)outp;                              // [16384][2]
    float*  out_ap  = outp + N_UE * 2;                            // [128][32]
    float2* out_eua = (float2*)(outp + N_UE * 2 + N_AP * 32);     // [E][2]
    float2* out_eau = (float2*)(outp + N_UE * 2 + N_AP * 32 + (size_t)NE * 2);

    float* ws = (float*)d_ws;
    float* x_ueA  = ws;          ws += N_UE * 32;
    float* x_ueB  = ws;          ws += N_UE * 32;
    float* x_apA  = ws;          ws += N_AP * 32;
    float* x_apB  = ws;          ws += N_AP * 32;
    float* agg_ue = ws;          ws += N_UE * 32;
    float* Qua    = ws;          ws += N_UE * 32;
    float* Pau    = ws;          ws += N_AP * 32;
    float2* RueA  = (float2*)ws; ws += N_UE * 2;
    float2* RueB  = (float2*)ws; ws += N_UE * 2;
    float2* RapA  = (float2*)ws; ws += N_AP * 2;
    float2* RapB  = (float2*)ws; ws += N_AP * 2;
    float* partial = ws;         ws += (size_t)NPART * 32;        // 2 MB
    int* cnt   = (int*)ws;       ws += N_UE;
    int* offs  = (int*)ws;       ws += N_UE + 4;
    int* histD = (int*)ws;       ws += NSB * N_AP;
    int* offsD = (int*)ws;       ws += NSB * N_AP;
    int* offsDnode = (int*)ws;   ws += N_AP + 4;
    int* invS  = (int*)ws;       ws += NE;                        // 8 MB
    int* invD  = (int*)ws;       ws += NE;                        // 8 MB
    int* dtS   = (int*)ws;       ws += NE;                        // 8 MB
    int* srcD  = (int*)ws;       ws += NE;                        // 8 MB
    float2* attS_A = (float2*)ws; ws += (size_t)NE * 2;           // 16 MB
    float2* attS_B = (float2*)ws; ws += (size_t)NE * 2;           // 16 MB
    float2* attD_A = (float2*)ws; ws += (size_t)NE * 2;           // 16 MB
    float2* attD_B = (float2*)ws; ws += (size_t)NE * 2;           // 16 MB
    int* histS = (int*)attS_B;   // alias 16 MB: dead before attS_B written (layer 2)
    int* baseS = (int*)attD_B;   // alias 16 MB: dead before attD_B written (layer 2)

    dim3 blk(256);

    // ---- sorts ----
    hist_src<<<NSB, blk, 0, stream>>>(src, histS);
    colscan_kernel<<<N_UE / 256, blk, 0, stream>>>(histS, baseS, cnt);
    scan_kernel<<<1, blk, 0, stream>>>(cnt, offs);
    scatter_src<<<NSB, blk, 0, stream>>>(src, dst, e0au, baseS, offs, dtS, attS_A, invS);
    hist_dst<<<NSB, blk, 0, stream>>>(dst, histD);
    scan_dst<<<1, dim3(128), 0, stream>>>(histD, offsD, offsDnode);
    scatter_dst<<<NSB, blk, 0, stream>>>(src, dst, e0ua, offsD, srcD, attD_A, invD);

    init_kernel<<<N_UE * 32 / 256, blk, 0, stream>>>(x_ue, Wm1_ua, bm1_ua, bm1_au, Qua, Pau);

    // ---- layer 1 ----
    ue_pass<false><<<N_UE / 8, blk, 0, stream>>>(
        offs, dtS, attS_A, nullptr, nullptr, nullptr, nullptr,
        Pau, Wm1_au, agg_ue);
    ap_pass<false><<<NPART / 8, blk, 0, stream>>>(
        offsDnode, srcD, attD_A, nullptr, nullptr, nullptr, nullptr,
        Qua, Wm1_ua + 32, partial);
    node_ue_kernel<true, false><<<N_UE / 256, blk, 0, stream>>>(
        x_ue, agg_ue, Wu1_ue, bu1_ue, Wm_ua, bm_ua, We1_ua, We1_au,
        nullptr, nullptr, nullptr, nullptr,
        x_ueA, Qua, RueA, RueB, nullptr);
    node_ap_kernel<true, false><<<N_AP, blk, 0, stream>>>(
        partial, nullptr, Wu1_ap, bu1_ap, Wm_au, bm_au,
        We1_ua + 64, be1_ua, We1_au + 64, be1_au,
        x_apA, Pau, RapA, RapB);

    // ---- layer 2 (edge-update 1 fused) ----
    ue_pass<true><<<N_UE / 8, blk, 0, stream>>>(
        offs, dtS, attS_A, attS_B, RueB, RapB, We1_au + 128,
        Pau, Wm_au + 1024, agg_ue);
    ap_pass<true><<<NPART / 8, blk, 0, stream>>>(
        offsDnode, srcD, attD_A, attD_B, RueA, RapA, We1_ua + 128,
        Qua, Wm_ua + 1024, partial);
    node_ue_kernel<false, false><<<N_UE / 256, blk, 0, stream>>>(
        x_ueA, agg_ue, Wu_ue, bu_ue, Wm_ua + 1088, bm_ua + 32, We_ua, We_au,
        nullptr, nullptr, nullptr, nullptr,
        x_ueB, Qua, RueA, RueB, nullptr);
    node_ap_kernel<false, false><<<N_AP, blk, 0, stream>>>(
        partial, x_apA, Wu_ap, bu_ap, Wm_au + 1088, bm_au + 32,
        We_ua + 64, be_ua, We_au + 64, be_au,
        x_apB, Pau, RapA, RapB);

    // ---- layer 3 (edge-update 2 fused) ----
    ue_pass<true><<<N_UE / 8, blk, 0, stream>>>(
        offs, dtS, attS_B, attS_A, RueB, RapB, We_au + 128,
        Pau, Wm_au + 2112, agg_ue);
    ap_pass<true><<<NPART / 8, blk, 0, stream>>>(
        offsDnode, srcD, attD_B, attD_A, RueA, RapA, We_ua + 128,
        Qua, Wm_ua + 2112, partial);
    node_ue_kernel<false, false><<<N_UE / 256, blk, 0, stream>>>(
        x_ueB, agg_ue, Wu_ue + 2048, bu_ue + 32, Wm_ua + 2176, bm_ua + 64,
        We_ua + 132, We_au + 132,
        nullptr, nullptr, nullptr, nullptr,
        x_ueA, Qua, RueA, RueB, nullptr);
    node_ap_kernel<false, false><<<N_AP, blk, 0, stream>>>(
        partial, x_apB, Wu_ap + 2048, bu_ap + 32, Wm_au + 2176, bm_au + 64,
        We_ua + 196, be_ua + 2, We_au + 196, be_au + 2,
        x_apA, Pau, RapA, RapB);

    // ---- layer 4 (edge-update 3 fused) ----
    ue_pass<true><<<N_UE / 8, blk, 0, stream>>>(
        offs, dtS, attS_A, attS_B, RueB, RapB, We_au + 260,
        Pau, Wm_au + 3200, agg_ue);
    ap_pass<true><<<NPART / 8, blk, 0, stream>>>(
        offsDnode, srcD, attD_A, attD_B, RueA, RapA, We_ua + 260,
        Qua, Wm_ua + 3200, partial);
    node_ue_kernel<false, true><<<N_UE / 256, blk, 0, stream>>>(
        x_ueA, agg_ue, Wu_ue + 4096, bu_ue + 64, nullptr, nullptr,
        We_ua + 264, We_au + 264,
        Wp1, bp1, Wp2, bp2,
        x_ueB, nullptr, RueA, RueB, out_ue);
    node_ap_kernel<false, true><<<N_AP, blk, 0, stream>>>(
        partial, x_apA, Wu_ap + 4096, bu_ap + 64, nullptr, nullptr,
        We_ua + 328, be_ua + 4, We_au + 328, be_au + 4,
        out_ap, nullptr, RapA, RapB);

    // ---- final edge update (layer 4), original order ----
    final_edge<<<NE / 256, blk, 0, stream>>>(
        src, dst, invS, invD, attS_B, attD_B,
        RueA, RueB, RapA, RapB,
        We_ua + 392, We_au + 392, out_eua, out_eau);
}